// Round 8
// baseline (46.354 us; speedup 1.0000x reference)
//
#include <hip/hip_runtime.h>

// GSplat renderer, separable-Gaussian, LDS-resident, 4x4-per-thread tiling.
// R7 lesson: per-CU LDS pipe was 2x oversubscribed (10 ds_reads per 40 VALU).
// New tiling: thread = 4 cols x 4 rows -> per gaussian per wave exactly
// 3 ds_read_b128 (ex quad per-lane, ey quad broadcast, col broadcast) for
// 80 VALU ops => VALU-bound (288 LDS-cy vs 320 VALU-cy per CU per i).
// Block = 256 threads = 16 rows x 256 cols, one 64-gaussian chunk.
// Grid (16 rowgroups, 32 parts) = 512 blocks = 2 blocks/CU, 2 waves/SIMD.

constexpr int HH = 256;
constexpr int WW = 256;
constexpr int PIX = HH * WW;
constexpr int NCHUNK = 64;          // gaussians per block
constexpr int RPB = 16;             // rows per block
constexpr float COORD_STEP = 2.0f / 255.0f;  // linspace(-1,1,256) step

__global__ __launch_bounds__(256) void gs_accum(
    const float* __restrict__ means, const float* __restrict__ scales,
    const float* __restrict__ opac, const float* __restrict__ colors,
    float* __restrict__ partials) {
  __shared__ float pxL[NCHUNK], pyL[NCHUNK], kL[NCHUNK];
  __shared__ float4 colL[NCHUNK];
  __shared__ float exL[NCHUNK][WW];   // 64 KB
  __shared__ float eyL[NCHUNK][RPB];  // 4 KB

  const int t = threadIdx.x;
  const int lane = t & 63;
  const int rq = __builtin_amdgcn_readfirstlane(t >> 6);  // wave id 0..3
  const int rowbase = blockIdx.x * RPB;
  const int part = blockIdx.y;
  const int n0 = part * NCHUNK;

  // --- per-gaussian params (threads 0..63) ---
  if (t < NCHUNK) {
    int n = n0 + t;
    float mx = means[3 * n], my = means[3 * n + 1], mz = means[3 * n + 2];
    float scl = fmaxf((scales[3 * n] + scales[3 * n + 1] + scales[3 * n + 2]) * (1.0f / 3.0f), 1e-4f);
    float op = opac[n];
    float rzs = 1.0f / (fabsf(mz) + 1.0f);
    float px = tanhf(mx * rzs);
    float py = tanhf(my * rzs);
    float sigma = fminf(fmaxf(scl * rzs, 0.02f), 0.5f);
    float inv_s = 1.0f / sigma;
    float K = -0.72134752044f * inv_s * inv_s;  // -0.5/ln2 * inv_s^2
    pxL[t] = px;
    pyL[t] = py;
    kL[t] = K;
    colL[t] = make_float4(op * colors[3 * n], op * colors[3 * n + 1],
                          op * colors[3 * n + 2], op);
  }
  __syncthreads();

  // --- tables into LDS ---
  {
    // exL[k][t]: thread t owns absolute column t (block spans full width).
    float ccol = -1.0f + COORD_STEP * (float)t;
#pragma unroll 4
    for (int k = 0; k < NCHUNK; ++k) {
      float dx = ccol - pxL[k];
      exL[k][t] = exp2f(kL[k] * dx * dx);
    }
    // eyL[i][r]: 64x16 entries, 4 per thread.
#pragma unroll
    for (int k = 0; k < (NCHUNK * RPB) / 256; ++k) {  // 4
      int idx = t + (k << 8);
      int i = idx >> 4;   // 0..63
      int r = idx & 15;   // 0..15
      float crow = -1.0f + COORD_STEP * (float)(rowbase + r);
      float dy = crow - pyL[i];
      eyL[i][r] = exp2f(kL[i] * dy * dy);
    }
  }
  __syncthreads();

  // --- main contraction: 3 b128 LDS reads + 80 VALU per gaussian ---
  float4 acc[4][4];  // [row][col], each float4 = (r,g,b,denom)
#pragma unroll
  for (int r = 0; r < 4; ++r)
#pragma unroll
    for (int c = 0; c < 4; ++c) acc[r][c] = make_float4(0.f, 0.f, 0.f, 0.f);

  const int c0 = lane << 2;      // first of this thread's 4 columns
  const int eyOff = rq << 2;     // first of this wave's 4 rows (scalar)

#pragma unroll 2
  for (int i = 0; i < NCHUNK; ++i) {
    float4 ex4 = *(const float4*)&exL[i][c0];
    float4 ey4 = *(const float4*)&eyL[i][eyOff];
    float4 cc = colL[i];
    float eyv[4] = {ey4.x, ey4.y, ey4.z, ey4.w};
    float exv[4] = {ex4.x, ex4.y, ex4.z, ex4.w};
#pragma unroll
    for (int r = 0; r < 4; ++r) {
#pragma unroll
      for (int c = 0; c < 4; ++c) {
        float w = eyv[r] * exv[c];
        acc[r][c].x = fmaf(w, cc.x, acc[r][c].x);
        acc[r][c].y = fmaf(w, cc.y, acc[r][c].y);
        acc[r][c].z = fmaf(w, cc.z, acc[r][c].z);
        acc[r][c].w = fmaf(w, cc.w, acc[r][c].w);
      }
    }
  }

  // --- epilogue: transpose in registers, coalesced b128 stores ---
  float* pb = partials + (size_t)part * 4 * PIX;
#pragma unroll
  for (int r = 0; r < 4; ++r) {
    int row = rowbase + (rq << 2) + r;
    float* rowp = pb + row * WW + c0;
    *(float4*)&rowp[0 * PIX] = make_float4(acc[r][0].x, acc[r][1].x, acc[r][2].x, acc[r][3].x);
    *(float4*)&rowp[1 * PIX] = make_float4(acc[r][0].y, acc[r][1].y, acc[r][2].y, acc[r][3].y);
    *(float4*)&rowp[2 * PIX] = make_float4(acc[r][0].z, acc[r][1].z, acc[r][2].z, acc[r][3].z);
    *(float4*)&rowp[3 * PIX] = make_float4(acc[r][0].w, acc[r][1].w, acc[r][2].w, acc[r][3].w);
  }
}

// grid = PIX/4/256 = 64 blocks; thread = one 4-px group, all 4 planes.
__global__ __launch_bounds__(256) void gs_finalize(
    const float4* __restrict__ partials4, float4* __restrict__ out4,
    int parts) {
  int g = blockIdx.x * 256 + threadIdx.x;  // 0..PIX/4-1
  float4 sr = make_float4(0.f, 0.f, 0.f, 0.f);
  float4 sg = sr, sb = sr, sd = sr;
  const float4* p = partials4 + g;
#pragma unroll 4
  for (int part = 0; part < parts; ++part) {
    float4 a = p[0 * (PIX / 4)];
    float4 b = p[1 * (PIX / 4)];
    float4 c = p[2 * (PIX / 4)];
    float4 d = p[3 * (PIX / 4)];
    sr.x += a.x; sr.y += a.y; sr.z += a.z; sr.w += a.w;
    sg.x += b.x; sg.y += b.y; sg.z += b.z; sg.w += b.w;
    sb.x += c.x; sb.y += c.y; sb.z += c.z; sb.w += c.w;
    sd.x += d.x; sd.y += d.y; sd.z += d.z; sd.w += d.w;
    p += 4 * (PIX / 4);
  }
  float4 inv;
  inv.x = 1.0f / fmaxf(sd.x, 1e-5f);
  inv.y = 1.0f / fmaxf(sd.y, 1e-5f);
  inv.z = 1.0f / fmaxf(sd.z, 1e-5f);
  inv.w = 1.0f / fmaxf(sd.w, 1e-5f);
#define GS_FIN(S, CH)                                      \
  out4[(CH) * (PIX / 4) + g] = make_float4(                \
      fminf(fmaxf((S).x * inv.x, 0.0f), 1.0f),             \
      fminf(fmaxf((S).y * inv.y, 0.0f), 1.0f),             \
      fminf(fmaxf((S).z * inv.z, 0.0f), 1.0f),             \
      fminf(fmaxf((S).w * inv.w, 0.0f), 1.0f));
  GS_FIN(sr, 0)
  GS_FIN(sg, 1)
  GS_FIN(sb, 2)
#undef GS_FIN
}

extern "C" void kernel_launch(void* const* d_in, const int* in_sizes, int n_in,
                              void* d_out, int out_size, void* d_ws, size_t ws_size,
                              hipStream_t stream) {
  const float* means = (const float*)d_in[0];
  // d_in[1] = quats (unused by reference)
  const float* scales = (const float*)d_in[2];
  const float* opac = (const float*)d_in[3];
  const float* colors = (const float*)d_in[4];
  float* out = (float*)d_out;
  int N = in_sizes[0] / 3;  // 2048

  int parts = N / NCHUNK;  // 32 for N=2048
  // Workspace: partials [parts][4][PIX] float = 32 MB for N=2048.
  float* partials = (float*)d_ws;

  gs_accum<<<dim3(HH / RPB, parts), 256, 0, stream>>>(
      means, scales, opac, colors, partials);
  gs_finalize<<<PIX / 4 / 256, 256, 0, stream>>>(
      (const float4*)partials, (float4*)out, parts);
}

// Round 9
// 35.916 us; speedup vs baseline: 1.2906x; 1.2906x over previous
//
#include <hip/hip_runtime.h>

// GSplat renderer, separable-Gaussian, LDS-resident.
// Constraints learned R3-R8: (1) >=40 VALU insts per ~3 wide LDS ops per
// wave-iteration; (2) accumulator <=32 VGPRs (R8's 64-reg acc likely fell off
// the occupancy cliff); (3) partials <=16 MB; (4) explicit register rotation
// at distance 2 — the compiler does not rotate loads across iterations.
// Geometry: block = 64 cols x 32 rows, thread = 2 cols x 4 rows,
// NCHUNK = 128 gaussians/block, grid (4,8,16) = 512 blocks, LDS 51.5 KB.

constexpr int HH = 256;
constexpr int WW = 256;
constexpr int PIX = HH * WW;
constexpr int NCHUNK = 128;  // gaussians per block (= N/parts)
constexpr int CPB = 64;      // cols per block
constexpr int RPB = 32;      // rows per block
constexpr float COORD_STEP = 2.0f / 255.0f;  // linspace(-1,1,256) step

__global__ __launch_bounds__(256) void gs_accum(
    const float* __restrict__ means, const float* __restrict__ scales,
    const float* __restrict__ opac, const float* __restrict__ colors,
    float* __restrict__ partials) {
  __shared__ float pxL[NCHUNK], pyL[NCHUNK], kL[NCHUNK];
  __shared__ float4 colL[NCHUNK];
  __shared__ float exL[NCHUNK][CPB];   // 32 KB
  __shared__ float eyL[NCHUNK][RPB];   // 16 KB

  const int t = threadIdx.x;
  const int n0 = blockIdx.z * NCHUNK;

  // --- per-gaussian params (threads 0..127) ---
  if (t < NCHUNK) {
    int n = n0 + t;
    float mx = means[3 * n], my = means[3 * n + 1], mz = means[3 * n + 2];
    float scl = fmaxf((scales[3 * n] + scales[3 * n + 1] + scales[3 * n + 2]) * (1.0f / 3.0f), 1e-4f);
    float op = opac[n];
    float rzs = 1.0f / (fabsf(mz) + 1.0f);
    float px = tanhf(mx * rzs);
    float py = tanhf(my * rzs);
    float sigma = fminf(fmaxf(scl * rzs, 0.02f), 0.5f);
    float inv_s = 1.0f / sigma;
    float K = -0.72134752044f * inv_s * inv_s;  // -0.5/ln2 * inv_s^2
    pxL[t] = px;
    pyL[t] = py;
    kL[t] = K;
    colL[t] = make_float4(op * colors[3 * n], op * colors[3 * n + 1],
                          op * colors[3 * n + 2], op);
  }
  __syncthreads();

  // --- tables into LDS (absolute coordinates — R6 lesson) ---
  {
    int c = t & 63;
    int kb = t >> 6;  // 0..3
    float ccol = -1.0f + COORD_STEP * (float)(blockIdx.x * CPB + c);
#pragma unroll 8
    for (int j = 0; j < NCHUNK / 4; ++j) {
      int k = kb + (j << 2);
      float dx = ccol - pxL[k];
      exL[k][c] = exp2f(kL[k] * dx * dx);
    }
    int r = t & 31;
    int kb2 = t >> 5;  // 0..7
    float crow = -1.0f + COORD_STEP * (float)(blockIdx.y * RPB + r);
#pragma unroll 8
    for (int j = 0; j < NCHUNK / 8; ++j) {
      int k = kb2 + (j << 3);
      float dy = crow - pyL[k];
      eyL[k][r] = exp2f(kL[k] * dy * dy);
    }
  }
  __syncthreads();

  // --- main contraction ---
  const int c0 = (t & 31) << 1;  // local col: 0,2,..,62
  const int r0 = (t >> 5) << 2;  // local row: 0,4,..,28

  float4 acc[4][2];
#pragma unroll
  for (int r = 0; r < 4; ++r) {
    acc[r][0] = make_float4(0.f, 0.f, 0.f, 0.f);
    acc[r][1] = make_float4(0.f, 0.f, 0.f, 0.f);
  }

  // Distance-2 software pipeline: banks for i and i+1, prefetch i+2/i+3.
  float2 ex0 = *(const float2*)&exL[0][c0];
  float4 ey0 = *(const float4*)&eyL[0][r0];
  float4 cc0 = colL[0];
  float2 ex1 = *(const float2*)&exL[1][c0];
  float4 ey1 = *(const float4*)&eyL[1][r0];
  float4 cc1 = colL[1];

#define GS_BODY(EX, EY, CC)                               \
  {                                                       \
    float eyarr[4] = {(EY).x, (EY).y, (EY).z, (EY).w};    \
    _Pragma("unroll")                                     \
    for (int r = 0; r < 4; ++r) {                         \
      float w0 = eyarr[r] * (EX).x;                       \
      acc[r][0].x = fmaf(w0, (CC).x, acc[r][0].x);        \
      acc[r][0].y = fmaf(w0, (CC).y, acc[r][0].y);        \
      acc[r][0].z = fmaf(w0, (CC).z, acc[r][0].z);        \
      acc[r][0].w = fmaf(w0, (CC).w, acc[r][0].w);        \
      float w1 = eyarr[r] * (EX).y;                       \
      acc[r][1].x = fmaf(w1, (CC).x, acc[r][1].x);        \
      acc[r][1].y = fmaf(w1, (CC).y, acc[r][1].y);        \
      acc[r][1].z = fmaf(w1, (CC).z, acc[r][1].z);        \
      acc[r][1].w = fmaf(w1, (CC).w, acc[r][1].w);        \
    }                                                     \
  }

#pragma unroll 1
  for (int i = 0; i < NCHUNK; i += 2) {
    int ia = (i + 2) & (NCHUNK - 1);  // wraps to 0 at tail: harmless re-read
    int ib = (i + 3) & (NCHUNK - 1);
    float2 exa = *(const float2*)&exL[ia][c0];
    float4 eya = *(const float4*)&eyL[ia][r0];
    float4 cca = colL[ia];
    GS_BODY(ex0, ey0, cc0)
    float2 exb = *(const float2*)&exL[ib][c0];
    float4 eyb = *(const float4*)&eyL[ib][r0];
    float4 ccb = colL[ib];
    GS_BODY(ex1, ey1, cc1)
    ex0 = exa; ey0 = eya; cc0 = cca;
    ex1 = exb; ey1 = eyb; cc1 = ccb;
  }
#undef GS_BODY

  // --- epilogue: float2 stores per plane/row ---
  float* pb = partials + (size_t)blockIdx.z * 4 * PIX;
  int colabs = blockIdx.x * CPB + c0;
#pragma unroll
  for (int r = 0; r < 4; ++r) {
    int row = blockIdx.y * RPB + r0 + r;
    float* rowp = pb + row * WW + colabs;
    *(float2*)(rowp + 0 * PIX) = make_float2(acc[r][0].x, acc[r][1].x);
    *(float2*)(rowp + 1 * PIX) = make_float2(acc[r][0].y, acc[r][1].y);
    *(float2*)(rowp + 2 * PIX) = make_float2(acc[r][0].z, acc[r][1].z);
    *(float2*)(rowp + 3 * PIX) = make_float2(acc[r][0].w, acc[r][1].w);
  }
}

// grid = PIX/4/256 = 64 blocks; thread = one 4-px group, all 4 planes.
__global__ __launch_bounds__(256) void gs_finalize(
    const float4* __restrict__ partials4, float4* __restrict__ out4,
    int parts) {
  int g = blockIdx.x * 256 + threadIdx.x;  // 0..PIX/4-1
  float4 sr = make_float4(0.f, 0.f, 0.f, 0.f);
  float4 sg = sr, sb = sr, sd = sr;
  const float4* p = partials4 + g;
#pragma unroll 4
  for (int part = 0; part < parts; ++part) {
    float4 a = p[0 * (PIX / 4)];
    float4 b = p[1 * (PIX / 4)];
    float4 c = p[2 * (PIX / 4)];
    float4 d = p[3 * (PIX / 4)];
    sr.x += a.x; sr.y += a.y; sr.z += a.z; sr.w += a.w;
    sg.x += b.x; sg.y += b.y; sg.z += b.z; sg.w += b.w;
    sb.x += c.x; sb.y += c.y; sb.z += c.z; sb.w += c.w;
    sd.x += d.x; sd.y += d.y; sd.z += d.z; sd.w += d.w;
    p += 4 * (PIX / 4);
  }
  float4 inv;
  inv.x = 1.0f / fmaxf(sd.x, 1e-5f);
  inv.y = 1.0f / fmaxf(sd.y, 1e-5f);
  inv.z = 1.0f / fmaxf(sd.z, 1e-5f);
  inv.w = 1.0f / fmaxf(sd.w, 1e-5f);
#define GS_FIN(S, CH)                                      \
  out4[(CH) * (PIX / 4) + g] = make_float4(                \
      fminf(fmaxf((S).x * inv.x, 0.0f), 1.0f),             \
      fminf(fmaxf((S).y * inv.y, 0.0f), 1.0f),             \
      fminf(fmaxf((S).z * inv.z, 0.0f), 1.0f),             \
      fminf(fmaxf((S).w * inv.w, 0.0f), 1.0f));
  GS_FIN(sr, 0)
  GS_FIN(sg, 1)
  GS_FIN(sb, 2)
#undef GS_FIN
}

extern "C" void kernel_launch(void* const* d_in, const int* in_sizes, int n_in,
                              void* d_out, int out_size, void* d_ws, size_t ws_size,
                              hipStream_t stream) {
  const float* means = (const float*)d_in[0];
  // d_in[1] = quats (unused by reference)
  const float* scales = (const float*)d_in[2];
  const float* opac = (const float*)d_in[3];
  const float* colors = (const float*)d_in[4];
  float* out = (float*)d_out;
  int N = in_sizes[0] / 3;  // 2048

  int parts = N / NCHUNK;  // 16 for N=2048
  // Workspace: partials [parts][4][PIX] float = 16 MB.
  float* partials = (float*)d_ws;

  gs_accum<<<dim3(WW / CPB, HH / RPB, parts), 256, 0, stream>>>(
      means, scales, opac, colors, partials);
  gs_finalize<<<PIX / 4 / 256, 256, 0, stream>>>(
      (const float4*)partials, (float4*)out, parts);
}